// Round 5
// baseline (449.980 us; speedup 1.0000x reference)
//
#include <hip/hip_runtime.h>
#include <stdint.h>

#define N_ROWS 16384
#define DIM    512

typedef float v4f __attribute__((ext_vector_type(4)));
typedef int   v8i __attribute__((ext_vector_type(8)));
typedef unsigned long long u64;
typedef unsigned char u8;

__device__ __forceinline__ v8i make_v8i(int4 lo, int4 hi) {
    v8i r;
    r[0] = lo.x; r[1] = lo.y; r[2] = lo.z; r[3] = lo.w;
    r[4] = hi.x; r[5] = hi.y; r[6] = hi.z; r[7] = hi.w;
    return r;
}

// Monotonic float -> sortable u32 key
__device__ __forceinline__ unsigned fkey(float f) {
    unsigned u = __float_as_uint(f);
    return (u & 0x80000000u) ? ~u : (u | 0x80000000u);
}

// Async global->LDS, 16B per lane. LDS dest = wave-uniform base + lane*16.
__device__ __forceinline__ void gload_lds16(const void* g, void* l) {
    __builtin_amdgcn_global_load_lds(
        (const __attribute__((address_space(1))) unsigned int*)g,
        (__attribute__((address_space(3))) unsigned int*)l,
        16, 0, 0);
}

// ---------------- kernel 1: fp32 -> fp8 e4m3 convert (+ table zero-init) ----------------
// HW RNE conversion; x ~ N(0,1) so no saturation concerns (e4m3 max 448).
__global__ __launch_bounds__(256)
void convert_fp8_kernel(const float* __restrict__ x, unsigned* __restrict__ x8,
                        u64* __restrict__ table) {
    int tid    = blockIdx.x * blockDim.x + threadIdx.x;
    int stride = gridDim.x * blockDim.x;
    if (tid < N_ROWS) table[tid] = 0;
    const float4* x4 = (const float4*)x;
    const int n4 = (N_ROWS * DIM) / 4;
    for (int i = tid; i < n4; i += stride) {
        float4 v = x4[i];
        int b = __builtin_amdgcn_cvt_pk_fp8_f32(v.x, v.y, 0, false);   // bytes 0,1
        b     = __builtin_amdgcn_cvt_pk_fp8_f32(v.z, v.w, b, true);    // bytes 2,3
        x8[i] = (unsigned)b;
    }
}

// ---------------- kernel 2: symmetric tiled fp8 GEMM + fused argmax ----------------
// Triangle-fold schedule (r3): b = u*64 + p; u<=p -> (127-p,127-u), else (p,u-1).
// r5: fp8 e4m3 data, BK=128, 4 K-rounds, mfma_scale_f32_16x16x128_f8f6f4 with
// unit scales (E8M0 byte 0x7F = 2^0) -> 2x MFMA rate, 0.5x staging bytes, 0.5x
// barrier-drain events vs bf16/BK=64. Single-buffer 2-barrier K-loop (r4 showed
// explicit dbuf loses to the occupancy it costs).
// LDS chunk layout, L in [0,1024) per matrix-round (16B chunks):
//   row(L) = (L>>9)*64 + ((L>>6)&3)*16 + (L&15); k16(L) = ((L>>4)&3)*2 + ((L>>8)&1)
// Frag read (half h, frag rf, slice s): addr = h*8192 + s*4096 + rf*1024 + lane*16
//   -> row = base+lane15, k = quad*32 + s*16 + [0,16): exactly the v8i operand's
//   k-ascending 32 bytes per lane (lo=s0, hi=s1). Conflict-free lane-sequential.
__global__ __launch_bounds__(256)
void argmax_dots_kernel(const u8* __restrict__ xb, u64* __restrict__ table) {
    __shared__ __attribute__((aligned(16))) u8 ldsA[128 * 128];  // 16 KB
    __shared__ __attribute__((aligned(16))) u8 ldsB[128 * 128];  // 16 KB

    const int u = blockIdx.x >> 6;
    const int p = blockIdx.x & 63;
    const int rT = (u <= p) ? (127 - p) : p;
    const int cT = (u <= p) ? (127 - u) : (u - 1);

    const int t      = threadIdx.x;
    const int lane   = t & 63;
    const int wave   = t >> 6;
    const int lane15 = lane & 15;
    const int quad   = lane >> 4;
    const int rh = wave >> 1;               // row half of the 128x128 tile
    const int ch = wave & 1;                // col half

    const int rowBase = rT * 128;
    const int colBase = cT * 128;

    // Per-thread staging sources, 4 issues per matrix per round.
    const u8* gA[4];
    const u8* gB[4];
#pragma unroll
    for (int j = 0; j < 4; ++j) {
        const int L = j * 256 + t;
        const int srow = ((L >> 9) << 6) + (((L >> 6) & 3) << 4) + (L & 15);
        const int sk16 = (((L >> 4) & 3) << 1) + ((L >> 8) & 1);
        gA[j] = xb + (size_t)(rowBase + srow) * DIM + sk16 * 16;
        gB[j] = xb + (size_t)(colBase + srow) * DIM + sk16 * 16;
    }
    const int dstOff = wave * 1024;         // + j*4096 per issue (bytes)

    v4f acc[4][4];
#pragma unroll
    for (int rf = 0; rf < 4; ++rf)
#pragma unroll
        for (int cf = 0; cf < 4; ++cf) {
            v4f z = {0.f, 0.f, 0.f, 0.f};
            acc[rf][cf] = z;
        }

#pragma unroll
    for (int k = 0; k < 4; ++k) {           // 4 K-rounds of BK=128
        const int kk = k * 128;             // byte offset (1 B/elem)
#pragma unroll
        for (int j = 0; j < 4; ++j) {
            gload_lds16(gA[j] + kk, (char*)ldsA + j * 4096 + dstOff);
            gload_lds16(gB[j] + kk, (char*)ldsB + j * 4096 + dstOff);
        }
        __syncthreads();                    // drains vmcnt; loads visible

        v8i a8[4], b8[4];
#pragma unroll
        for (int rf = 0; rf < 4; ++rf) {
            int4 lo = *(const int4*)(ldsA + rh * 8192 +        rf * 1024 + lane * 16);
            int4 hi = *(const int4*)(ldsA + rh * 8192 + 4096 + rf * 1024 + lane * 16);
            a8[rf] = make_v8i(lo, hi);
        }
#pragma unroll
        for (int cf = 0; cf < 4; ++cf) {
            int4 lo = *(const int4*)(ldsB + ch * 8192 +        cf * 1024 + lane * 16);
            int4 hi = *(const int4*)(ldsB + ch * 8192 + 4096 + cf * 1024 + lane * 16);
            b8[cf] = make_v8i(lo, hi);
        }
#pragma unroll
        for (int rf = 0; rf < 4; ++rf)
#pragma unroll
            for (int cf = 0; cf < 4; ++cf)
                acc[rf][cf] = __builtin_amdgcn_mfma_scale_f32_16x16x128_f8f6f4(
                    a8[rf], b8[cf], acc[rf][cf],
                    0, 0,                        // cbsz=fp8(e4m3), blgp=fp8(e4m3)
                    0, 0x7F7F7F7F,               // opsel_a, scale_a = 2^0
                    0, 0x7F7F7F7F);              // opsel_b, scale_b = 2^0
        __syncthreads();                    // protect LDS from next round's writes
    }

    // ---- epilogue: row-side argmax (C/D layout: col=lane15+16*cf, row=quad*4+e) ----
    const int colLane = colBase + ch * 64 + lane15;
#pragma unroll
    for (int rf = 0; rf < 4; ++rf) {
#pragma unroll
        for (int e = 0; e < 4; ++e) {
            const int row = rowBase + rh * 64 + rf * 16 + quad * 4 + e;
            float bv = -3.0e38f;
            int   bc = 0;
#pragma unroll
            for (int cf = 0; cf < 4; ++cf) {
                const float v = acc[rf][cf][e];
                const int col = colLane + cf * 16;
                if (v > bv && col != row) { bv = v; bc = col; }
            }
            u64 packed = ((u64)fkey(bv) << 32) | (unsigned)(~bc);  // ~col: ties->lowest idx
#pragma unroll
            for (int m = 1; m < 16; m <<= 1) {
                u64 o = __shfl_xor(packed, m, 64);
                if (o > packed) packed = o;
            }
            if (lane15 == 0) atomicMax(&table[row], packed);
        }
    }

    // ---- epilogue: col-side (transposed) argmax for off-diagonal tiles ----
    if (rT != cT) {
#pragma unroll
        for (int cf = 0; cf < 4; ++cf) {
            const int col = colLane + cf * 16;
            float bv = -3.0e38f;
            int   br_ = 0;
#pragma unroll
            for (int rf = 0; rf < 4; ++rf)
#pragma unroll
                for (int e = 0; e < 4; ++e) {
                    const float v = acc[rf][cf][e];
                    const int row = rowBase + rh * 64 + rf * 16 + quad * 4 + e;
                    if (v > bv) { bv = v; br_ = row; }
                }
            u64 packed = ((u64)fkey(bv) << 32) | (unsigned)(~br_);
            u64 o = __shfl_xor(packed, 16, 64); if (o > packed) packed = o;
            o     = __shfl_xor(packed, 32, 64); if (o > packed) packed = o;
            if (quad == 0) atomicMax(&table[col], packed);
        }
    }
}

// ---------------- kernel 3: rho + loss epilogue (fp32 exact) ----------------
__global__ __launch_bounds__(256)
void rho_loss_kernel(const float* __restrict__ x, const u64* __restrict__ table,
                     float* __restrict__ out) {
    const int lane = threadIdx.x & 63;
    const int wave = threadIdx.x >> 6;
    const int waveGlobal = blockIdx.x * 4 + wave;   // 2048 waves

    float local = 0.f;
    for (int r8 = 0; r8 < 8; ++r8) {
        const int row = waveGlobal * 8 + r8;
        const u64 packed = table[row];
        const int nb = (int)(~(unsigned)(packed & 0xFFFFFFFFu));

        const float4* xr = (const float4*)(x + (size_t)row * DIM);
        const float4* xn = (const float4*)(x + (size_t)nb  * DIM);
        float s = 0.f;
#pragma unroll
        for (int tt = 0; tt < 2; ++tt) {
            float4 a = xr[lane * 2 + tt];
            float4 b = xn[lane * 2 + tt];
            float d0 = a.x - b.x + 1e-6f;
            float d1 = a.y - b.y + 1e-6f;
            float d2 = a.z - b.z + 1e-6f;
            float d3 = a.w - b.w + 1e-6f;
            s += d0 * d0 + d1 * d1 + d2 * d2 + d3 * d3;
        }
#pragma unroll
        for (int m = 1; m < 64; m <<= 1) s += __shfl_xor(s, m, 64);

        if (lane == 0) {
            float rho = sqrtf(s);
            local += logf(rho + 1e-8f);
        }
    }
    if (lane == 0) atomicAdd(out, -local * (1.0f / 16384.0f));
}

extern "C" void kernel_launch(void* const* d_in, const int* in_sizes, int n_in,
                              void* d_out, int out_size, void* d_ws, size_t ws_size,
                              hipStream_t stream) {
    const float* x = (const float*)d_in[0];

    // Workspace: [0, 8 MiB) fp8 x; then 16384 x u64 argmax table.
    u8*   xb    = (u8*)d_ws;
    u64*  table = (u64*)((char*)d_ws + (size_t)N_ROWS * DIM);
    float* out  = (float*)d_out;

    hipMemsetAsync(out, 0, sizeof(float), stream);

    convert_fp8_kernel<<<2048, 256, 0, stream>>>(x, (unsigned*)xb, table);
    argmax_dots_kernel<<<8256, 256, 0, stream>>>(xb, table);
    rho_loss_kernel<<<512, 256, 0, stream>>>(x, table, out);
}

// Round 6
// 360.072 us; speedup vs baseline: 1.2497x; 1.2497x over previous
//
#include <hip/hip_runtime.h>
#include <stdint.h>

#define N_ROWS 16384
#define DIM    512

typedef __bf16 v8bf __attribute__((ext_vector_type(8)));
typedef float  v4f  __attribute__((ext_vector_type(4)));
typedef unsigned long long u64;

union I4B8 { int4 i; v8bf b; };
__device__ __forceinline__ v8bf as_v8bf(int4 v) { I4B8 u; u.i = v; return u.b; }

// Round-to-nearest-even fp32 -> bf16
__device__ __forceinline__ ushort bf16_rne(float f) {
    unsigned u = __float_as_uint(f);
    unsigned r = u + 0x7FFFu + ((u >> 16) & 1u);
    return (ushort)(r >> 16);
}

// Monotonic float -> sortable u32 key
__device__ __forceinline__ unsigned fkey(float f) {
    unsigned u = __float_as_uint(f);
    return (u & 0x80000000u) ? ~u : (u | 0x80000000u);
}

// Async global->LDS, 16B per lane. LDS dest = wave-uniform base + lane*16.
__device__ __forceinline__ void gload_lds16(const void* g, void* l) {
    __builtin_amdgcn_global_load_lds(
        (const __attribute__((address_space(1))) unsigned int*)g,
        (__attribute__((address_space(3))) unsigned int*)l,
        16, 0, 0);
}

// ---------------- kernel 1: fp32 -> bf16 convert (+ table zero-init) ----------------
__global__ __launch_bounds__(256)
void convert_bf16_kernel(const float* __restrict__ x, ushort* __restrict__ xb,
                         u64* __restrict__ table) {
    int tid    = blockIdx.x * blockDim.x + threadIdx.x;
    int stride = gridDim.x * blockDim.x;
    if (tid < N_ROWS) table[tid] = 0;
    const float4* x4  = (const float4*)x;
    ushort4*      xb4 = (ushort4*)xb;
    const int n4 = (N_ROWS * DIM) / 4;
    for (int i = tid; i < n4; i += stride) {
        float4 v = x4[i];
        ushort4 o;
        o.x = bf16_rne(v.x);
        o.y = bf16_rne(v.y);
        o.z = bf16_rne(v.z);
        o.w = bf16_rne(v.w);
        xb4[i] = o;
    }
}

// ---------------- kernel 2: symmetric tiled GEMM + fused argmax ----------------
// Triangle-fold schedule (r3): b = u*64 + p; u<=p -> (127-p,127-u), else (p,u-1).
// r6: XOR-swizzled row-major LDS tiles. Tile = 128 rows x 64 cols bf16 =
// 128 rows x 8 chunks of 16 B. LDS slot (row, sk) holds global chunk
// (row, kc = sk ^ (row&7)):
//  * staging lane L: row=L>>3, slot_k=L&7 -> gsrc kc=(L&7)^(row&7). Each 8-lane
//    group loads one full 128 B row (permuted within the row) -> fully
//    coalesced, 4x less L2 line traffic than r3's 512B-strided gather (the
//    measured r3 wall: 2.11 GB x 4 amplification / 287us ~= 29 TB/s ~= L2 peak).
//  * frag read (s, quad q, lane15 l): wants kc=s*4+q of row rf*16+l -> slot
//    row*8 + ((s*4+q)^(l&7)); lanes 0..15 cover all 8 bank residues twice
//    -> 2-way aliasing = free (m136). Conflict-free AND coalesced.
__global__ __launch_bounds__(256)
void argmax_dots_kernel(const ushort* __restrict__ xb, u64* __restrict__ table) {
    __shared__ __attribute__((aligned(16))) ushort ldsA[128 * 64];  // 16 KB
    __shared__ __attribute__((aligned(16))) ushort ldsB[128 * 64];  // 16 KB

    const int u = blockIdx.x >> 6;
    const int p = blockIdx.x & 63;
    const int rT = (u <= p) ? (127 - p) : p;
    const int cT = (u <= p) ? (127 - u) : (u - 1);

    const int t      = threadIdx.x;
    const int lane   = t & 63;
    const int wave   = t >> 6;
    const int lane15 = lane & 15;
    const int quad   = lane >> 4;
    const int rh = wave >> 1;               // row half of the 128x128 tile
    const int ch = wave & 1;                // col half

    const int rowBase = rT * 128;
    const int colBase = cT * 128;

    // Staging sources: 4 issues per matrix per round, coalesced row-major.
    const ushort* gA[4];
    const ushort* gB[4];
#pragma unroll
    for (int j = 0; j < 4; ++j) {
        const int L   = j * 256 + t;
        const int row = L >> 3;
        const int kc  = (L & 7) ^ (row & 7);       // swizzled source chunk
        gA[j] = xb + (size_t)(rowBase + row) * DIM + kc * 8;
        gB[j] = xb + (size_t)(colBase + row) * DIM + kc * 8;
    }
    const int dstOff = wave * 1024;         // + j*4096 per issue (bytes)

    // Per-lane swizzled frag byte offsets within a tile:
    //   addr(row half h, rf, s) = (h*64 + rf*16 + lane15)*128 + xorS[s]
    const int xor0 = ((quad     ) ^ (lane15 & 7)) << 4;    // s=0
    const int xor1 = ((quad | 4 ) ^ (lane15 & 7)) << 4;    // s=1

    v4f acc[4][4];
#pragma unroll
    for (int rf = 0; rf < 4; ++rf)
#pragma unroll
        for (int cf = 0; cf < 4; ++cf) {
            v4f z = {0.f, 0.f, 0.f, 0.f};
            acc[rf][cf] = z;
        }

    for (int kk = 0; kk < DIM; kk += 64) {  // 8 rounds
#pragma unroll
        for (int j = 0; j < 4; ++j) {
            gload_lds16(gA[j] + kk, (char*)ldsA + j * 4096 + dstOff);
            gload_lds16(gB[j] + kk, (char*)ldsB + j * 4096 + dstOff);
        }
        __syncthreads();                    // drains vmcnt; loads visible

#pragma unroll
        for (int s = 0; s < 2; ++s) {
            const int xs = s ? xor1 : xor0;
            int4 ar[4], br[4];
#pragma unroll
            for (int rf = 0; rf < 4; ++rf)
                ar[rf] = *(const int4*)((const char*)ldsA
                          + (rh * 64 + rf * 16 + lane15) * 128 + xs);
#pragma unroll
            for (int cf = 0; cf < 4; ++cf)
                br[cf] = *(const int4*)((const char*)ldsB
                          + (ch * 64 + cf * 16 + lane15) * 128 + xs);
#pragma unroll
            for (int rf = 0; rf < 4; ++rf)
#pragma unroll
                for (int cf = 0; cf < 4; ++cf)
                    acc[rf][cf] = __builtin_amdgcn_mfma_f32_16x16x32_bf16(
                        as_v8bf(ar[rf]), as_v8bf(br[cf]), acc[rf][cf], 0, 0, 0);
        }
        __syncthreads();                    // protect LDS from next round's writes
    }

    // ---- epilogue: row-side argmax (C/D layout: col=lane15+16*cf, row=quad*4+e) ----
    const int colLane = colBase + ch * 64 + lane15;
#pragma unroll
    for (int rf = 0; rf < 4; ++rf) {
#pragma unroll
        for (int e = 0; e < 4; ++e) {
            const int row = rowBase + rh * 64 + rf * 16 + quad * 4 + e;
            float bv = -3.0e38f;
            int   bc = 0;
#pragma unroll
            for (int cf = 0; cf < 4; ++cf) {
                const float v = acc[rf][cf][e];
                const int col = colLane + cf * 16;
                if (v > bv && col != row) { bv = v; bc = col; }
            }
            u64 packed = ((u64)fkey(bv) << 32) | (unsigned)(~bc);  // ~col: ties->lowest idx
#pragma unroll
            for (int m = 1; m < 16; m <<= 1) {
                u64 o = __shfl_xor(packed, m, 64);
                if (o > packed) packed = o;
            }
            if (lane15 == 0) atomicMax(&table[row], packed);
        }
    }

    // ---- epilogue: col-side (transposed) argmax for off-diagonal tiles ----
    if (rT != cT) {
#pragma unroll
        for (int cf = 0; cf < 4; ++cf) {
            const int col = colLane + cf * 16;
            float bv = -3.0e38f;
            int   br_ = 0;
#pragma unroll
            for (int rf = 0; rf < 4; ++rf)
#pragma unroll
                for (int e = 0; e < 4; ++e) {
                    const float v = acc[rf][cf][e];
                    const int row = rowBase + rh * 64 + rf * 16 + quad * 4 + e;
                    if (v > bv) { bv = v; br_ = row; }
                }
            u64 packed = ((u64)fkey(bv) << 32) | (unsigned)(~br_);
            u64 o = __shfl_xor(packed, 16, 64); if (o > packed) packed = o;
            o     = __shfl_xor(packed, 32, 64); if (o > packed) packed = o;
            if (quad == 0) atomicMax(&table[col], packed);
        }
    }
}

// ---------------- kernel 3: rho + loss epilogue (fp32 exact) ----------------
__global__ __launch_bounds__(256)
void rho_loss_kernel(const float* __restrict__ x, const u64* __restrict__ table,
                     float* __restrict__ out) {
    const int lane = threadIdx.x & 63;
    const int wave = threadIdx.x >> 6;
    const int waveGlobal = blockIdx.x * 4 + wave;   // 2048 waves

    float local = 0.f;
    for (int r8 = 0; r8 < 8; ++r8) {
        const int row = waveGlobal * 8 + r8;
        const u64 packed = table[row];
        const int nb = (int)(~(unsigned)(packed & 0xFFFFFFFFu));

        const float4* xr = (const float4*)(x + (size_t)row * DIM);
        const float4* xn = (const float4*)(x + (size_t)nb  * DIM);
        float s = 0.f;
#pragma unroll
        for (int tt = 0; tt < 2; ++tt) {
            float4 a = xr[lane * 2 + tt];
            float4 b = xn[lane * 2 + tt];
            float d0 = a.x - b.x + 1e-6f;
            float d1 = a.y - b.y + 1e-6f;
            float d2 = a.z - b.z + 1e-6f;
            float d3 = a.w - b.w + 1e-6f;
            s += d0 * d0 + d1 * d1 + d2 * d2 + d3 * d3;
        }
#pragma unroll
        for (int m = 1; m < 64; m <<= 1) s += __shfl_xor(s, m, 64);

        if (lane == 0) {
            float rho = sqrtf(s);
            local += logf(rho + 1e-8f);
        }
    }
    if (lane == 0) atomicAdd(out, -local * (1.0f / 16384.0f));
}

extern "C" void kernel_launch(void* const* d_in, const int* in_sizes, int n_in,
                              void* d_out, int out_size, void* d_ws, size_t ws_size,
                              hipStream_t stream) {
    const float* x = (const float*)d_in[0];

    // Workspace: [0, 16 MiB) bf16 x; then 16384 x u64 argmax table.
    ushort* xb    = (ushort*)d_ws;
    u64*    table = (u64*)((char*)d_ws + (size_t)N_ROWS * DIM * sizeof(ushort));
    float*  out   = (float*)d_out;

    hipMemsetAsync(out, 0, sizeof(float), stream);

    convert_bf16_kernel<<<2048, 256, 0, stream>>>(x, xb, table);
    argmax_dots_kernel<<<8256, 256, 0, stream>>>(xb, table);
    rho_loss_kernel<<<512, 256, 0, stream>>>(x, table, out);
}